// Round 1
// 153.702 us; speedup vs baseline: 1.0080x; 1.0080x over previous
//
#include <hip/hip_runtime.h>
#include <math.h>

#define N_BATCH 256
#define C_CH    2048
#define HW      49
#define SIZE7   7
#define BLOCK   1024
#define NWAVES  16                    // 1024 / 64
#define C_PER_W (C_CH / NWAVES)       // 128 channels per wave

// Fused kernel: one block per batch element n.
// Phase 1: stage all weight rows (W1r0, W1r1, W2r0, W2r1) into LDS (32 KB).
// Phase 2: wave w reduces channels [w*128, (w+1)*128) over all 49 positions:
//   q0: sum x            (argmax of channel-mean)
//   q1: sum x*W1[0,c]    (anchor dot, row 0)
//   q2: sum x*W1[1,c]    (anchor dot, row 1)
//   q3: sum x*W2[0,c]    (pred term, out 0)
//   q4: sum x*W2[1,c]    (pred term, out 1)
// Phase 3: 320-thread LDS reduction across the 16 waves.
// Phase 4: wave 0 does argmax + epilogue and writes out[n, 0:49].
__global__ __launch_bounds__(BLOCK) void rpp_fused_kernel(
    const float* __restrict__ x, const float* __restrict__ Wlin,
    const float* __restrict__ b, float* __restrict__ out) {
  const int n    = blockIdx.x;
  const int tid  = threadIdx.x;
  const int lane = tid & 63;
  const int wave = tid >> 6;

  __shared__ __align__(16) float w_s[4][C_CH];   // 32 KB: W1r0, W1r1, W2r0, W2r1
  __shared__ float red[NWAVES][5][64];           // 20 KB

  // Stage weights. Wlin is (2, 2C): W1[o,c] = Wlin[o*2C + c], W2[o,c] = Wlin[o*2C + C + c]
  for (int i = tid; i < 4 * C_CH; i += BLOCK) {
    const int q = i >> 11;           // / C_CH
    const int c = i & (C_CH - 1);
    const int off = (q & 1) * (2 * C_CH) + (q >> 1) * C_CH;
    w_s[q][c] = Wlin[off + c];
  }
  __syncthreads();

  // Lane p reads x[n, c, p]; lanes >= 49 clamp to p=0 (same cache line, masked later).
  const int lp = (lane < HW) ? lane : 0;
  const int cb = wave * C_PER_W;
  const float* xp = x + (size_t)n * C_CH * HW + (size_t)cb * HW + lp;

  float a0 = 0.f, a1 = 0.f, a2 = 0.f, a3 = 0.f, a4 = 0.f;
#pragma unroll 2
  for (int c = 0; c < C_PER_W; c += 8) {
    const float v0 = xp[0 * HW];
    const float v1 = xp[1 * HW];
    const float v2 = xp[2 * HW];
    const float v3 = xp[3 * HW];
    const float v4 = xp[4 * HW];
    const float v5 = xp[5 * HW];
    const float v6 = xp[6 * HW];
    const float v7 = xp[7 * HW];
    xp += 8 * HW;
    const float4 wa0 = *(const float4*)&w_s[0][cb + c];
    const float4 wa1 = *(const float4*)&w_s[0][cb + c + 4];
    const float4 wb0 = *(const float4*)&w_s[1][cb + c];
    const float4 wb1 = *(const float4*)&w_s[1][cb + c + 4];
    const float4 wc0 = *(const float4*)&w_s[2][cb + c];
    const float4 wc1 = *(const float4*)&w_s[2][cb + c + 4];
    const float4 wd0 = *(const float4*)&w_s[3][cb + c];
    const float4 wd1 = *(const float4*)&w_s[3][cb + c + 4];
    a0 += ((v0 + v1) + (v2 + v3)) + ((v4 + v5) + (v6 + v7));
    a1 = fmaf(v0, wa0.x, fmaf(v1, wa0.y, fmaf(v2, wa0.z, fmaf(v3, wa0.w, a1))));
    a1 = fmaf(v4, wa1.x, fmaf(v5, wa1.y, fmaf(v6, wa1.z, fmaf(v7, wa1.w, a1))));
    a2 = fmaf(v0, wb0.x, fmaf(v1, wb0.y, fmaf(v2, wb0.z, fmaf(v3, wb0.w, a2))));
    a2 = fmaf(v4, wb1.x, fmaf(v5, wb1.y, fmaf(v6, wb1.z, fmaf(v7, wb1.w, a2))));
    a3 = fmaf(v0, wc0.x, fmaf(v1, wc0.y, fmaf(v2, wc0.z, fmaf(v3, wc0.w, a3))));
    a3 = fmaf(v4, wc1.x, fmaf(v5, wc1.y, fmaf(v6, wc1.z, fmaf(v7, wc1.w, a3))));
    a4 = fmaf(v0, wd0.x, fmaf(v1, wd0.y, fmaf(v2, wd0.z, fmaf(v3, wd0.w, a4))));
    a4 = fmaf(v4, wd1.x, fmaf(v5, wd1.y, fmaf(v6, wd1.z, fmaf(v7, wd1.w, a4))));
  }

  red[wave][0][lane] = a0;
  red[wave][1][lane] = a1;
  red[wave][2][lane] = a2;
  red[wave][3][lane] = a3;
  red[wave][4][lane] = a4;
  __syncthreads();

  // Reduce 16 waves -> red[0][q][l] with 320 threads (each owns one (q,l) slot).
  if (tid < 5 * 64) {
    const int q = tid >> 6;
    const int l = tid & 63;
    float s = 0.f;
#pragma unroll
    for (int w = 0; w < NWAVES; w++) s += red[w][q][l];
    red[0][q][l] = s;
  }
  __syncthreads();

  if (wave == 0) {
    const float s0 = red[0][0][lane];
    const float s1 = red[0][1][lane];
    const float s2 = red[0][2][lane];
    const float s3 = red[0][3][lane];
    const float s4 = red[0][4][lane];

    // argmax over p<49 of channel-sum (same order as mean); first-max tie-break.
    float v = (lane < HW) ? s0 : -INFINITY;
    int vi = lane;
#pragma unroll
    for (int off = 32; off; off >>= 1) {
      const float ov = __shfl_down(v, off);
      const int oi = __shfl_down(vi, off);
      if (ov > v || (ov == v && oi < vi)) { v = ov; vi = oi; }
    }
    const int idx = __shfl(vi, 0);

    // anchor dot products: (max_feat @ W1^T)[n, o]
    const float anc0 = __shfl(s1, idx);
    const float anc1 = __shfl(s2, idx);
    const float b0 = b[0], b1 = b[1];

    float pred0 = fmaxf(s3 + anc0 + b0, 0.f);
    float pred1 = fmaxf(s4 + anc1 + b1, 0.f);
    if (lane == idx) { pred0 = 0.f; pred1 = 0.f; }

    const int li = lane / SIZE7, lj = lane % SIZE7;
    const int ai = idx / SIZE7, aj = idx % SIZE7;
    const float ri = (float)(li - ai) * (1.0f / SIZE7);
    const float rj = (float)(lj - aj) * (1.0f / SIZE7);
    const float rdist = sqrtf(ri * ri + rj * rj);
    // (atan2/pi + 1)/2 ; atan2f(0,0)=0 matches jnp at the anchor.
    const float rangle = atan2f(rj, ri) * 0.15915494309189535f + 0.5f;

    float dl = pred0 - rdist;
    dl *= dl;
    float gap = pred1 - rangle;
    if (gap < 0.f) gap += 1.f;

    // mean of gap over the 49 valid positions
    float g = (lane < HW) ? gap : 0.f;
#pragma unroll
    for (int off = 32; off; off >>= 1) g += __shfl_down(g, off);
    const float mean = __shfl(g, 0) * (1.0f / HW);
    gap -= mean;

    if (lane < HW) out[(size_t)n * HW + lane] = dl + gap * gap;
  }
}

extern "C" void kernel_launch(void* const* d_in, const int* in_sizes, int n_in,
                              void* d_out, int out_size, void* d_ws, size_t ws_size,
                              hipStream_t stream) {
  const float* x    = (const float*)d_in[0];
  const float* Wlin = (const float*)d_in[1];
  const float* b    = (const float*)d_in[2];
  float* out = (float*)d_out;
  (void)d_ws; (void)ws_size;

  hipLaunchKernelGGL(rpp_fused_kernel, dim3(N_BATCH), dim3(BLOCK), 0,
                     stream, x, Wlin, b, out);
}

// Round 2
// 153.178 us; speedup vs baseline: 1.0115x; 1.0034x over previous
//
#include <hip/hip_runtime.h>
#include <math.h>

#define N_BATCH 256
#define C_CH    2048
#define HW      49
#define SIZE7   7
#define BLOCK   1024
#define NWAVES  16                   // 1024 / 64
#define TC      256                  // channels per LDS tile
#define NT      (C_CH / TC)          // 8 tiles
#define TILE_F  (TC * HW)            // 12544 floats = 49 KB
#define TILE_V4 (TILE_F / 4)         // 3136 float4 per tile
#define CPWT    (TC / NWAVES)        // 16 channels per wave per tile

// One block per batch element n. 2-phase pipeline (guide T3 minimum form):
//   prologue: STAGE(tile0); vmcnt(0); barrier
//   loop:     STAGE(next) ; compute(cur from LDS) ; vmcnt(0); barrier
// Staging uses global_load_lds width=16 with a LINEAR LDS destination
// (lane i of a full wave -> base + 16*i), which is the required layout.
// Pass k=3 activates exactly wave 0 (tid<64), so no partially-active waves.
// Weights are read as wave-uniform float4 via readfirstlane -> s_load path,
// keeping the LDS pipe free for the x reads.
__global__ __launch_bounds__(BLOCK) void rpp_fused_kernel(
    const float* __restrict__ x, const float* __restrict__ Wlin,
    const float* __restrict__ b, float* __restrict__ out) {
  const int n    = blockIdx.x;
  const int tid  = threadIdx.x;
  const int lane = tid & 63;
  const int wave = tid >> 6;

  __shared__ __align__(16) float xs[2][TILE_F];   // 100,352 B (double buffer)
  __shared__ float red[NWAVES][5][64];            //  20,480 B

  const size_t xbase = (size_t)n * (C_CH * HW);
  const int lp = (lane < HW) ? lane : 0;          // lanes >=49 alias p=0 (masked later)

#define STAGE(DB, T)                                                          \
  do {                                                                        \
    const float* gsrc_ = x + xbase + (size_t)(T) * TILE_F;                    \
    for (int k_ = 0; k_ < 4; ++k_) {                                          \
      const int i_ = tid + k_ * BLOCK;                                        \
      if (i_ < TILE_V4) {                                                     \
        __builtin_amdgcn_global_load_lds(                                     \
            (const __attribute__((address_space(1))) void*)(gsrc_ + i_ * 4),  \
            (__attribute__((address_space(3))) void*)(&xs[DB][i_ * 4]),       \
            16, 0, 0);                                                        \
      }                                                                       \
    }                                                                         \
  } while (0)

  float a0 = 0.f, a1 = 0.f, a2 = 0.f, a3 = 0.f, a4 = 0.f;

  STAGE(0, 0);
  asm volatile("s_waitcnt vmcnt(0)" ::: "memory");
  __syncthreads();

  int db = 0;
  for (int t = 0; t < NT; ++t) {
    if (t + 1 < NT) STAGE(db ^ 1, t + 1);   // prefetch next tile (other buffer)

    const float* xsl = &xs[db][wave * CPWT * HW + lp];
    const int c0 = t * TC + wave * CPWT;    // wave-uniform global channel base
#pragma unroll
    for (int k = 0; k < CPWT; k += 4) {
      const int cu = __builtin_amdgcn_readfirstlane(c0 + k);
      // Wlin is (2, 2C): W1[o,c]=Wlin[o*2C+c], W2[o,c]=Wlin[o*2C+C+c]
      const float4 wA = *(const float4*)(Wlin + cu);              // W1 row0 -> a1
      const float4 wB = *(const float4*)(Wlin + 2 * C_CH + cu);   // W1 row1 -> a2
      const float4 wC = *(const float4*)(Wlin + C_CH + cu);       // W2 row0 -> a3
      const float4 wD = *(const float4*)(Wlin + 3 * C_CH + cu);   // W2 row1 -> a4
      const float v0 = xsl[(k + 0) * HW];
      const float v1 = xsl[(k + 1) * HW];
      const float v2 = xsl[(k + 2) * HW];
      const float v3 = xsl[(k + 3) * HW];
      a0 += (v0 + v1) + (v2 + v3);
      a1 = fmaf(v0, wA.x, fmaf(v1, wA.y, fmaf(v2, wA.z, fmaf(v3, wA.w, a1))));
      a2 = fmaf(v0, wB.x, fmaf(v1, wB.y, fmaf(v2, wB.z, fmaf(v3, wB.w, a2))));
      a3 = fmaf(v0, wC.x, fmaf(v1, wC.y, fmaf(v2, wC.z, fmaf(v3, wC.w, a3))));
      a4 = fmaf(v0, wD.x, fmaf(v1, wD.y, fmaf(v2, wD.z, fmaf(v3, wD.w, a4))));
    }

    asm volatile("s_waitcnt vmcnt(0)" ::: "memory");  // next tile landed
    __syncthreads();                                  // all waves done with cur
    db ^= 1;
  }

  red[wave][0][lane] = a0;
  red[wave][1][lane] = a1;
  red[wave][2][lane] = a2;
  red[wave][3][lane] = a3;
  red[wave][4][lane] = a4;
  __syncthreads();

  // Reduce 16 waves -> red[0][q][l] with 320 threads (one (q,l) slot each).
  if (tid < 5 * 64) {
    const int q = tid >> 6;
    const int l = tid & 63;
    float s = 0.f;
#pragma unroll
    for (int w = 0; w < NWAVES; w++) s += red[w][q][l];
    red[0][q][l] = s;
  }
  __syncthreads();

  if (wave == 0) {
    const float s0 = red[0][0][lane];
    const float s1 = red[0][1][lane];
    const float s2 = red[0][2][lane];
    const float s3 = red[0][3][lane];
    const float s4 = red[0][4][lane];

    // argmax over p<49 of channel-sum (same order as mean); first-max tie-break.
    float v = (lane < HW) ? s0 : -INFINITY;
    int vi = lane;
#pragma unroll
    for (int off = 32; off; off >>= 1) {
      const float ov = __shfl_down(v, off);
      const int oi = __shfl_down(vi, off);
      if (ov > v || (ov == v && oi < vi)) { v = ov; vi = oi; }
    }
    const int idx = __shfl(vi, 0);

    // anchor dot products: (max_feat @ W1^T)[n, o]
    const float anc0 = __shfl(s1, idx);
    const float anc1 = __shfl(s2, idx);
    const float b0 = b[0], b1 = b[1];

    float pred0 = fmaxf(s3 + anc0 + b0, 0.f);
    float pred1 = fmaxf(s4 + anc1 + b1, 0.f);
    if (lane == idx) { pred0 = 0.f; pred1 = 0.f; }

    const int li = lane / SIZE7, lj = lane % SIZE7;
    const int ai = idx / SIZE7, aj = idx % SIZE7;
    const float ri = (float)(li - ai) * (1.0f / SIZE7);
    const float rj = (float)(lj - aj) * (1.0f / SIZE7);
    const float rdist = sqrtf(ri * ri + rj * rj);
    // (atan2/pi + 1)/2 ; atan2f(0,0)=0 matches jnp at the anchor.
    const float rangle = atan2f(rj, ri) * 0.15915494309189535f + 0.5f;

    float dl = pred0 - rdist;
    dl *= dl;
    float gap = pred1 - rangle;
    if (gap < 0.f) gap += 1.f;

    // mean of gap over the 49 valid positions
    float g = (lane < HW) ? gap : 0.f;
#pragma unroll
    for (int off = 32; off; off >>= 1) g += __shfl_down(g, off);
    const float mean = __shfl(g, 0) * (1.0f / HW);
    gap -= mean;

    if (lane < HW) out[(size_t)n * HW + lane] = dl + gap * gap;
  }
#undef STAGE
}

extern "C" void kernel_launch(void* const* d_in, const int* in_sizes, int n_in,
                              void* d_out, int out_size, void* d_ws, size_t ws_size,
                              hipStream_t stream) {
  const float* x    = (const float*)d_in[0];
  const float* Wlin = (const float*)d_in[1];
  const float* b    = (const float*)d_in[2];
  float* out = (float*)d_out;
  (void)d_ws; (void)ws_size;

  hipLaunchKernelGGL(rpp_fused_kernel, dim3(N_BATCH), dim3(BLOCK), 0,
                     stream, x, Wlin, b, out);
}